// Round 1
// baseline (350.049 us; speedup 1.0000x reference)
//
#include <hip/hip_runtime.h>

#define WIDTH  640
#define HEIGHT 384
#define PLANE  (WIDTH*HEIGHT)
#define STRIP  24
#define NSTRIP (HEIGHT/STRIP)   /* 16 */
#define GROUPS (STRIP/4)        /* 6 */
#define CS_PW  732              /* padded width: pidx(649)=730 */
#define SSIM_C1 1.0e-4f
#define SSIM_C2 9.0e-4f
#define INV_N  (1.0f/23592960.0f)

__device__ __forceinline__ int pidx(int x) { return x + (x >> 3); }

__global__ void ssim_init(float* out) { out[0] = 1.0f; }

__global__ __launch_bounds__(256, 2)
void ssim_kernel(const float* __restrict__ pred, const float* __restrict__ targ,
                 float* __restrict__ out)
{
    __shared__ float4 cs4[4][CS_PW];   // (p, t, p*p, t*t) column sums, 4 rows in flight
    __shared__ float  cs1[4][CS_PW];   // p*t column sums
    __shared__ float  red[4];

    const int tid   = threadIdx.x;
    const int plane = blockIdx.x >> 4;       // 96 planes
    const int strip = blockIdx.x & 15;       // 16 strips of 24 rows
    const int y0s   = strip * STRIP;
    const float* __restrict__ P = pred + plane * PLANE;
    const float* __restrict__ T = targ + plane * PLANE;

    // zero the horizontal halo columns (xi in [0,5) and [645,650)) once
    if (tid < 40) {
        int r = tid / 10, j = tid % 10;
        int xi = (j < 5) ? j : (640 + j);
        int q = pidx(xi);
        cs4[r][q] = make_float4(0.f, 0.f, 0.f, 0.f);
        cs1[r][q] = 0.f;
    }

    // Bootstrap: S[c][*] = column sums for output row (y0s - 1), i.e. rows [y0s-6, y0s+4]
    float S[3][5];
#pragma unroll
    for (int c = 0; c < 3; ++c)
#pragma unroll
        for (int q = 0; q < 5; ++q) S[c][q] = 0.f;

#pragma unroll
    for (int c = 0; c < 3; ++c) {
        int x = tid + (c << 8);
        if (x < WIDTH) {
            for (int yy = y0s - 6; yy <= y0s + 4; ++yy) {
                if (yy >= 0 && yy < HEIGHT) {
                    float pv = P[yy * WIDTH + x];
                    float tv = T[yy * WIDTH + x];
                    S[c][0] += pv;      S[c][1] += tv;
                    S[c][2] += pv * pv; S[c][3] += tv * tv;
                    S[c][4] += pv * tv;
                }
            }
        }
    }

    float acc = 0.f;
    const float inv121 = 1.0f / 121.0f;

    for (int g = 0; g < GROUPS; ++g) {
        const int y0 = y0s + (g << 2);

        // ---- Phase A: advance vertical sliding sums 4 rows, publish to LDS ----
#pragma unroll
        for (int c = 0; c < 3; ++c) {
            int x = tid + (c << 8);
            if (x < WIDTH) {
                int q = pidx(x + 5);
#pragma unroll
                for (int k = 0; k < 4; ++k) {
                    int yn = y0 + k + 5;
                    int yo = y0 + k - 6;
                    float pn = (yn < HEIGHT) ? P[yn * WIDTH + x] : 0.f;
                    float tn = (yn < HEIGHT) ? T[yn * WIDTH + x] : 0.f;
                    float po = (yo >= 0)     ? P[yo * WIDTH + x] : 0.f;
                    float to = (yo >= 0)     ? T[yo * WIDTH + x] : 0.f;
                    S[c][0] += pn - po;
                    S[c][1] += tn - to;
                    S[c][2] += pn * pn - po * po;
                    S[c][3] += tn * tn - to * to;
                    S[c][4] += pn * tn - po * to;
                    cs4[k][q] = make_float4(S[c][0], S[c][1], S[c][2], S[c][3]);
                    cs1[k][q] = S[c][4];
                }
            }
        }
        __syncthreads();

        // ---- Phase B: horizontal sliding window, 1 row per wave, 10 px per lane ----
        {
            const int r    = tid >> 6;
            const int lane = tid & 63;
            const int base = lane * 10;   // window xi-range for pixel i: [base+i, base+i+10]

            float4 w4[11]; float w1[11];
#pragma unroll
            for (int j = 0; j <= 10; ++j) {
                int q = pidx(base + j);
                w4[j] = cs4[r][q];
                w1[j] = cs1[r][q];
            }
            float4 B4 = w4[0]; float B1 = w1[0];
#pragma unroll
            for (int j = 1; j <= 10; ++j) {
                B4.x += w4[j].x; B4.y += w4[j].y;
                B4.z += w4[j].z; B4.w += w4[j].w;
                B1   += w1[j];
            }
#pragma unroll
            for (int i = 0; i < 10; ++i) {
                if (i > 0) {
                    int q = pidx(base + i + 10);
                    float4 n4 = cs4[r][q]; float n1 = cs1[r][q];
                    B4.x += n4.x - w4[i - 1].x;
                    B4.y += n4.y - w4[i - 1].y;
                    B4.z += n4.z - w4[i - 1].z;
                    B4.w += n4.w - w4[i - 1].w;
                    B1   += n1   - w1[i - 1];
                }
                float mp  = B4.x * inv121, mt = B4.y * inv121;
                float mpp = mp * mp, mtt = mt * mt, mpt = mp * mt;
                float sp  = B4.z * inv121 - mpp;
                float st  = B4.w * inv121 - mtt;
                float spt = B1   * inv121 - mpt;
                float num = (2.f * mpt + SSIM_C1) * (2.f * spt + SSIM_C2);
                float den = (mpp + mtt + SSIM_C1) * (sp + st + SSIM_C2);
                acc += num / den;
            }
        }
        __syncthreads();
    }

    // ---- reduction: wave shuffle -> LDS -> one atomic per block ----
#pragma unroll
    for (int off = 32; off >= 1; off >>= 1)
        acc += __shfl_down(acc, off);
    if ((tid & 63) == 0) red[tid >> 6] = acc;
    __syncthreads();
    if (tid == 0) {
        float s = red[0] + red[1] + red[2] + red[3];
        atomicAdd(out, -s * INV_N);
    }
}

extern "C" void kernel_launch(void* const* d_in, const int* in_sizes, int n_in,
                              void* d_out, int out_size, void* d_ws, size_t ws_size,
                              hipStream_t stream) {
    const float* pred = (const float*)d_in[0];
    const float* targ = (const float*)d_in[1];
    float* out = (float*)d_out;
    ssim_init<<<1, 1, 0, stream>>>(out);
    ssim_kernel<<<96 * NSTRIP, 256, 0, stream>>>(pred, targ, out);
}